// Round 1
// baseline (224.207 us; speedup 1.0000x reference)
//
#include <hip/hip_runtime.h>
#include <hip/hip_bf16.h>
#include <math.h>

typedef __attribute__((ext_vector_type(4))) float f32x4;
typedef __attribute__((ext_vector_type(4))) float fvec4;
typedef __attribute__((ext_vector_type(8))) short bf16x8_t;
typedef __attribute__((ext_vector_type(4))) short bf16x4_t;

static constexpr int BATCH = 4;
static constexpr int SEQ = 4096;
static constexpr int DM = 512;
static constexpr int DA = 128;
static constexpr int BN = BATCH * SEQ;  // 16384

static __device__ __forceinline__ unsigned short f2bf(float f) {
  unsigned u = __builtin_bit_cast(unsigned, f);
  u += 0x7fffu + ((u >> 16) & 1u);
  return (unsigned short)(u >> 16);
}

// ---------------------------------------------------------------------------
// Kernel 0: cast x -> bf16, transpose+cast W_qkv -> [384][512], W_out -> [512][128]
// ---------------------------------------------------------------------------
__global__ __launch_bounds__(256) void prep_kernel(
    const float* __restrict__ x, const float* __restrict__ Wqkv,
    const float* __restrict__ Wout, unsigned short* __restrict__ xbf,
    unsigned short* __restrict__ WqT, unsigned short* __restrict__ WoT) {
  long long i = ((long long)blockIdx.x * 256 + threadIdx.x) * 8;
  if (i < (long long)BN * DM) {
    fvec4 a = *(const fvec4*)&x[i];
    fvec4 b = *(const fvec4*)&x[i + 4];
    union { bf16x8_t v; unsigned short u[8]; } pk;
    pk.u[0] = f2bf(a[0]); pk.u[1] = f2bf(a[1]); pk.u[2] = f2bf(a[2]); pk.u[3] = f2bf(a[3]);
    pk.u[4] = f2bf(b[0]); pk.u[5] = f2bf(b[1]); pk.u[6] = f2bf(b[2]); pk.u[7] = f2bf(b[3]);
    *(bf16x8_t*)&xbf[i] = pk.v;
  }
  int t = blockIdx.x * 256 + threadIdx.x;
  if (t < 512 * 384) {
    int k = t / 384, n = t - k * 384;
    WqT[n * 512 + k] = f2bf(Wqkv[t]);
  }
  if (t < 128 * 512) {
    int k = t >> 9, n = t & 511;
    WoT[n * 128 + k] = f2bf(Wout[t]);
  }
}

// ---------------------------------------------------------------------------
// Kernel 1: QKV projection.  [16384,512] @ [512,384] + bias.
// q,k stored bf16 row-major [BN][128]; v stored transposed [B][128][4096].
// Fragment-major LDS: chunk id = ((tile*4 + kgroup)*16 + row16) -> 16B
// ---------------------------------------------------------------------------
__global__ __launch_bounds__(256) void qkv_kernel(
    const unsigned short* __restrict__ xbf, const unsigned short* __restrict__ WqT,
    const float* __restrict__ bias, unsigned short* __restrict__ qbf,
    unsigned short* __restrict__ kbf, unsigned short* __restrict__ vT) {
  __shared__ unsigned short Alds[64 * 32];
  __shared__ unsigned short Blds[64 * 32];

  const int m0 = blockIdx.x * 64;
  const int n0 = blockIdx.y * 64;
  const int tid = threadIdx.x;
  const int wave = tid >> 6, lane = tid & 63;
  const int g = lane >> 4, lr = lane & 15;
  const int sar = tid >> 2, sak = tid & 3;   // A staging: row 0..63, kgroup 0..3
  const int sbc = tid & 63, sbk = tid >> 6;  // B staging: col 0..63, kgroup 0..3

  f32x4 acc[4] = {};

  for (int kb = 0; kb < DM; kb += 32) {
    __syncthreads();
    {
      bf16x8_t v = *(const bf16x8_t*)&xbf[(size_t)(m0 + sar) * DM + kb + sak * 8];
      *(bf16x8_t*)&Alds[(((sar >> 4) * 4 + sak) * 16 + (sar & 15)) * 8] = v;
    }
    {
      bf16x8_t v = *(const bf16x8_t*)&WqT[(size_t)(n0 + sbc) * DM + kb + sbk * 8];
      *(bf16x8_t*)&Blds[(((sbc >> 4) * 4 + sbk) * 16 + (sbc & 15)) * 8] = v;
    }
    __syncthreads();
    bf16x8_t af = *(const bf16x8_t*)&Alds[((wave * 4 + g) * 16 + lr) * 8];
#pragma unroll
    for (int c = 0; c < 4; ++c) {
      bf16x8_t bfr = *(const bf16x8_t*)&Blds[((c * 4 + g) * 16 + lr) * 8];
      acc[c] = __builtin_amdgcn_mfma_f32_16x16x32_bf16(af, bfr, acc[c], 0, 0, 0);
    }
  }

  const int rowb = m0 + wave * 16 + g * 4;  // rows rowb..rowb+3
  if (n0 < 128) {
#pragma unroll
    for (int c = 0; c < 4; ++c) {
      int col = n0 + c * 16 + lr;
      float bv = bias[col];
#pragma unroll
      for (int r = 0; r < 4; ++r)
        qbf[(size_t)(rowb + r) * DA + col] = f2bf(acc[c][r] + bv);
    }
  } else if (n0 < 256) {
#pragma unroll
    for (int c = 0; c < 4; ++c) {
      int col = n0 + c * 16 + lr;
      float bv = bias[col];
#pragma unroll
      for (int r = 0; r < 4; ++r)
        kbf[(size_t)(rowb + r) * DA + (col - 128)] = f2bf(acc[c][r] + bv);
    }
  } else {
    int b = rowb >> 12, n = rowb & 4095;
#pragma unroll
    for (int c = 0; c < 4; ++c) {
      int col = n0 + c * 16 + lr;
      float bv = bias[col];
      int d = col - 256;
      union { bf16x4_t v; unsigned short u[4]; } pk;
#pragma unroll
      for (int r = 0; r < 4; ++r) pk.u[r] = f2bf(acc[c][r] + bv);
      *(bf16x4_t*)&vT[((size_t)(b * DA + d)) * SEQ + n] = pk.v;  // 4 consecutive n
    }
  }
}

// ---------------------------------------------------------------------------
// Kernel 2: causal flash attention.  Block = 4 waves x 16 q-rows = 64 rows.
// KV tiles of 64.  fp32 online softmax.  ctx = (attn@v) * key_mask, bf16.
// ---------------------------------------------------------------------------
__global__ __launch_bounds__(256) void attn_kernel(
    const unsigned short* __restrict__ qbf, const unsigned short* __restrict__ kbf,
    const unsigned short* __restrict__ vT, const float* __restrict__ key_mask,
    unsigned short* __restrict__ ctx) {
  __shared__ unsigned short Klds[64 * 128];  // [ct4][c4][g4][16][8]
  __shared__ unsigned short Vlds[128 * 64];  // [t8][c2][g4][16][8]
  __shared__ unsigned short Plds[4][1024];   // per-wave [c2][g4][16][8]

  const int bb = blockIdx.y;
  const int r0 = blockIdx.x * 64;
  const int tid = threadIdx.x;
  const int wave = tid >> 6, lane = tid & 63;
  const int g = lane >> 4, lr = lane & 15;
  const int qrow0 = r0 + wave * 16;
  const float scale = 0.08838834764831845f;  // 1/sqrt(128)

  bf16x8_t qf[4];
  {
    const unsigned short* qb = qbf + ((size_t)(bb * SEQ + qrow0 + lr)) * DA + g * 8;
#pragma unroll
    for (int c = 0; c < 4; ++c) qf[c] = *(const bf16x8_t*)(qb + c * 32);
  }

  f32x4 oacc[8] = {};
  float m_r[4] = {-INFINITY, -INFINITY, -INFINITY, -INFINITY};
  float l_r[4] = {0.f, 0.f, 0.f, 0.f};

  const int kv_end = r0 + 64;
  for (int kv0 = 0; kv0 < kv_end; kv0 += 64) {
    __syncthreads();
#pragma unroll
    for (int it = 0; it < 4; ++it) {  // stage K: 64 rows x 16 chunks
      int idx = it * 256 + tid;
      int r = idx >> 4, kc = idx & 15;
      bf16x8_t v = *(const bf16x8_t*)&kbf[((size_t)(bb * SEQ + kv0 + r)) * DA + kc * 8];
      *(bf16x8_t*)&Klds[((((r >> 4) * 4 + (kc >> 2)) * 4 + (kc & 3)) * 16 + (r & 15)) * 8] = v;
    }
#pragma unroll
    for (int it = 0; it < 4; ++it) {  // stage V^T: 128 d-rows x 8 chunks
      int idx = it * 256 + tid;
      int d = idx >> 3, kc = idx & 7;
      bf16x8_t v = *(const bf16x8_t*)&vT[((size_t)(bb * DA + d)) * SEQ + kv0 + kc * 8];
      *(bf16x8_t*)&Vlds[((((d >> 4) * 2 + (kc >> 2)) * 4 + (kc & 3)) * 16 + (d & 15)) * 8] = v;
    }
    __syncthreads();

    if (kv0 <= qrow0 + 15) {  // wave has live keys in this tile
      f32x4 sacc[4] = {};
#pragma unroll
      for (int ct = 0; ct < 4; ++ct)
#pragma unroll
        for (int c = 0; c < 4; ++c) {
          bf16x8_t kf = *(const bf16x8_t*)&Klds[(((ct * 4 + c) * 4 + g) * 16 + lr) * 8];
          sacc[ct] = __builtin_amdgcn_mfma_f32_16x16x32_bf16(qf[c], kf, sacc[ct], 0, 0, 0);
        }
      // causal mask (before scale, as in ref), then scale; row max
      float tmax[4] = {-INFINITY, -INFINITY, -INFINITY, -INFINITY};
#pragma unroll
      for (int ct = 0; ct < 4; ++ct) {
        int kj = kv0 + ct * 16 + lr;
#pragma unroll
        for (int r = 0; r < 4; ++r) {
          int qi = qrow0 + g * 4 + r;
          float s = (kj <= qi) ? sacc[ct][r] * scale : -INFINITY;
          sacc[ct][r] = s;
          tmax[r] = fmaxf(tmax[r], s);
        }
      }
#pragma unroll
      for (int msk = 1; msk <= 8; msk <<= 1)
#pragma unroll
        for (int r = 0; r < 4; ++r)
          tmax[r] = fmaxf(tmax[r], __shfl_xor(tmax[r], msk, 64));
      float alpha[4];
#pragma unroll
      for (int r = 0; r < 4; ++r) {
        float mn = fmaxf(m_r[r], tmax[r]);
        alpha[r] = __expf(m_r[r] - mn);
        m_r[r] = mn;
      }
      float rsum[4] = {0.f, 0.f, 0.f, 0.f};
#pragma unroll
      for (int ct = 0; ct < 4; ++ct)
#pragma unroll
        for (int r = 0; r < 4; ++r) {
          float p = __expf(sacc[ct][r] - m_r[r]);  // exp(-inf)=0 for masked
          sacc[ct][r] = p;
          rsum[r] += p;
        }
#pragma unroll
      for (int msk = 1; msk <= 8; msk <<= 1)
#pragma unroll
        for (int r = 0; r < 4; ++r) rsum[r] += __shfl_xor(rsum[r], msk, 64);
#pragma unroll
      for (int r = 0; r < 4; ++r) l_r[r] = l_r[r] * alpha[r] + rsum[r];
#pragma unroll
      for (int t = 0; t < 8; ++t)
#pragma unroll
        for (int r = 0; r < 4; ++r) oacc[t][r] *= alpha[r];

      // P -> per-wave LDS (bf16), fragment-major
      unsigned short* pw = Plds[wave];
#pragma unroll
      for (int ct = 0; ct < 4; ++ct) {
        int k = ct * 16 + lr;
        int cc = k >> 5, gg = (k >> 3) & 3, j = k & 7;
#pragma unroll
        for (int r = 0; r < 4; ++r)
          pw[(((cc * 4 + gg) * 16 + (g * 4 + r)) * 8) + j] = f2bf(sacc[ct][r]);
      }
      asm volatile("s_waitcnt lgkmcnt(0)" ::: "memory");
      __builtin_amdgcn_sched_barrier(0);
      bf16x8_t pf[2];
#pragma unroll
      for (int c = 0; c < 2; ++c)
        pf[c] = *(const bf16x8_t*)&pw[((c * 4 + g) * 16 + lr) * 8];
#pragma unroll
      for (int t = 0; t < 8; ++t)
#pragma unroll
        for (int c = 0; c < 2; ++c) {
          bf16x8_t vf = *(const bf16x8_t*)&Vlds[(((t * 2 + c) * 4 + g) * 16 + lr) * 8];
          oacc[t] = __builtin_amdgcn_mfma_f32_16x16x32_bf16(pf[c], vf, oacc[t], 0, 0, 0);
        }
    }
  }

#pragma unroll
  for (int r = 0; r < 4; ++r) {
    int qi = qrow0 + g * 4 + r;
    float km = key_mask[bb * SEQ + qi];
    float inv = km / l_r[r];
#pragma unroll
    for (int t = 0; t < 8; ++t)
      ctx[((size_t)(bb * SEQ + qi)) * DA + t * 16 + lr] = f2bf(oacc[t][r] * inv);
  }
}

// ---------------------------------------------------------------------------
// Kernel 3: output projection.  [16384,128] @ [128,512] + bias -> fp32 out
// ---------------------------------------------------------------------------
__global__ __launch_bounds__(256) void outproj_kernel(
    const unsigned short* __restrict__ ctx, const unsigned short* __restrict__ WoT,
    const float* __restrict__ bias, float* __restrict__ out) {
  __shared__ unsigned short Alds[64 * 32];
  __shared__ unsigned short Blds[64 * 32];

  const int m0 = blockIdx.x * 64;
  const int n0 = blockIdx.y * 64;
  const int tid = threadIdx.x;
  const int wave = tid >> 6, lane = tid & 63;
  const int g = lane >> 4, lr = lane & 15;
  const int sar = tid >> 2, sak = tid & 3;
  const int sbc = tid & 63, sbk = tid >> 6;

  f32x4 acc[4] = {};

  for (int kb = 0; kb < DA; kb += 32) {
    __syncthreads();
    {
      bf16x8_t v = *(const bf16x8_t*)&ctx[(size_t)(m0 + sar) * DA + kb + sak * 8];
      *(bf16x8_t*)&Alds[(((sar >> 4) * 4 + sak) * 16 + (sar & 15)) * 8] = v;
    }
    {
      bf16x8_t v = *(const bf16x8_t*)&WoT[(size_t)(n0 + sbc) * DA + kb + sbk * 8];
      *(bf16x8_t*)&Blds[(((sbc >> 4) * 4 + sbk) * 16 + (sbc & 15)) * 8] = v;
    }
    __syncthreads();
    bf16x8_t af = *(const bf16x8_t*)&Alds[((wave * 4 + g) * 16 + lr) * 8];
#pragma unroll
    for (int c = 0; c < 4; ++c) {
      bf16x8_t bfr = *(const bf16x8_t*)&Blds[((c * 4 + g) * 16 + lr) * 8];
      acc[c] = __builtin_amdgcn_mfma_f32_16x16x32_bf16(af, bfr, acc[c], 0, 0, 0);
    }
  }

  const int rowb = m0 + wave * 16 + g * 4;
#pragma unroll
  for (int c = 0; c < 4; ++c) {
    int col = n0 + c * 16 + lr;
    float bv = bias[col];
#pragma unroll
    for (int r = 0; r < 4; ++r)
      out[(size_t)(rowb + r) * DM + col] = acc[c][r] + bv;
  }
}

// ---------------------------------------------------------------------------
extern "C" void kernel_launch(void* const* d_in, const int* in_sizes, int n_in,
                              void* d_out, int out_size, void* d_ws, size_t ws_size,
                              hipStream_t stream) {
  const float* x = (const float*)d_in[0];
  const float* key_mask = (const float*)d_in[1];
  const float* W_qkv = (const float*)d_in[2];
  const float* b_qkv = (const float*)d_in[3];
  const float* W_out = (const float*)d_in[4];
  const float* b_out = (const float*)d_in[5];
  float* out = (float*)d_out;

  unsigned short* ws = (unsigned short*)d_ws;
  unsigned short* qbf = ws;                                // [BN][128]
  unsigned short* kbf = qbf + (size_t)BN * DA;             // [BN][128]
  unsigned short* vT = kbf + (size_t)BN * DA;              // [B][128][4096]
  unsigned short* ctx = vT + (size_t)BN * DA;              // [BN][128]
  unsigned short* xbf = ctx + (size_t)BN * DA;             // [BN][512]
  unsigned short* WqT = xbf + (size_t)BN * DM;             // [384][512]
  unsigned short* WoT = WqT + (size_t)384 * 512;           // [512][128]

  prep_kernel<<<dim3((BN * DM / 8 + 255) / 256), 256, 0, stream>>>(
      x, W_qkv, W_out, xbf, WqT, WoT);
  qkv_kernel<<<dim3(BN / 64, 6), 256, 0, stream>>>(xbf, WqT, b_qkv, qbf, kbf, vT);
  attn_kernel<<<dim3(SEQ / 64, BATCH), 256, 0, stream>>>(qbf, kbf, vT, key_mask, ctx);
  outproj_kernel<<<dim3(BN / 64, 8), 256, 0, stream>>>(ctx, WoT, b_out, out);
}

// Round 2
// 112.631 us; speedup vs baseline: 1.9906x; 1.9906x over previous
//
#include <hip/hip_runtime.h>
#include <hip/hip_bf16.h>
#include <math.h>

typedef __attribute__((ext_vector_type(4))) float f32x4;
typedef __attribute__((ext_vector_type(4))) float fvec4;
typedef __attribute__((ext_vector_type(8))) short bf16x8_t;
typedef __attribute__((ext_vector_type(4))) short bf16x4_t;

static constexpr int BATCH = 4;
static constexpr int SEQ = 4096;
static constexpr int DM = 512;
static constexpr int DA = 128;
static constexpr int BN = BATCH * SEQ;  // 16384
static constexpr int IPB = 160;         // split-KV items per batch
static constexpr int N_ITEMS = BATCH * IPB;  // 640

static __device__ __forceinline__ unsigned short f2bf(float f) {
  unsigned u = __builtin_bit_cast(unsigned, f);
  u += 0x7fffu + ((u >> 16) & 1u);
  return (unsigned short)(u >> 16);
}
static __device__ __forceinline__ float bf2f(unsigned short u) {
  return __builtin_bit_cast(float, ((unsigned)u) << 16);
}

#define GLDS16(gsrc, ldst)                                                        \
  __builtin_amdgcn_global_load_lds(                                               \
      (const __attribute__((address_space(1))) void*)(gsrc),                      \
      (__attribute__((address_space(3))) void*)(ldst), 16, 0, 0)

// ---------------------------------------------------------------------------
// Kernel 0: cast x -> bf16, transpose+cast W_qkv -> [384][512], W_out -> [512][128]
// ---------------------------------------------------------------------------
__global__ __launch_bounds__(256) void prep_kernel(
    const float* __restrict__ x, const float* __restrict__ Wqkv,
    const float* __restrict__ Wout, unsigned short* __restrict__ xbf,
    unsigned short* __restrict__ WqT, unsigned short* __restrict__ WoT) {
  long long i = ((long long)blockIdx.x * 256 + threadIdx.x) * 8;
  if (i < (long long)BN * DM) {
    fvec4 a = *(const fvec4*)&x[i];
    fvec4 b = *(const fvec4*)&x[i + 4];
    union { bf16x8_t v; unsigned short u[8]; } pk;
    pk.u[0] = f2bf(a[0]); pk.u[1] = f2bf(a[1]); pk.u[2] = f2bf(a[2]); pk.u[3] = f2bf(a[3]);
    pk.u[4] = f2bf(b[0]); pk.u[5] = f2bf(b[1]); pk.u[6] = f2bf(b[2]); pk.u[7] = f2bf(b[3]);
    *(bf16x8_t*)&xbf[i] = pk.v;
  }
  int t = blockIdx.x * 256 + threadIdx.x;
  if (t < 512 * 384) {
    int k = t / 384, n = t - k * 384;
    WqT[n * 512 + k] = f2bf(Wqkv[t]);
  }
  if (t < 128 * 512) {
    int k = t >> 9, n = t & 511;
    WoT[n * 128 + k] = f2bf(Wout[t]);
  }
}

// ---------------------------------------------------------------------------
// Kernel 1: QKV projection.  [16384,512] @ [512,384] + bias.
// q: bf16 row-major [BN][128].
// k,v: packed per-64-row-tile in LDS fragment-major unit order so attention
// staging is a pure linear copy (global_load_lds friendly):
//   kpk[tile][unit][pos][8]  unit=((r>>4)*4+(kc>>2))*4+(kc&3), pos=r&15, kc=kd>>3
//   vpk[tile][unit][pos][8]  unit=((d>>4)*2+(nc>>2))*4+(nc&3), pos=d&15, nc=nl>>3
// ---------------------------------------------------------------------------
__global__ __launch_bounds__(256) void qkv_kernel(
    const unsigned short* __restrict__ xbf, const unsigned short* __restrict__ WqT,
    const float* __restrict__ bias, unsigned short* __restrict__ qbf,
    unsigned short* __restrict__ kpk, unsigned short* __restrict__ vpk) {
  __shared__ unsigned short Alds[64 * 32];
  __shared__ unsigned short Blds[64 * 32];

  const int m0 = blockIdx.x * 64;
  const int n0 = blockIdx.y * 64;
  const int tid = threadIdx.x;
  const int wave = tid >> 6, lane = tid & 63;
  const int g = lane >> 4, lr = lane & 15;
  const int sar = tid >> 2, sak = tid & 3;
  const int sbc = tid & 63, sbk = tid >> 6;

  f32x4 acc[4] = {};

  for (int kb = 0; kb < DM; kb += 32) {
    __syncthreads();
    {
      bf16x8_t v = *(const bf16x8_t*)&xbf[(size_t)(m0 + sar) * DM + kb + sak * 8];
      *(bf16x8_t*)&Alds[(((sar >> 4) * 4 + sak) * 16 + (sar & 15)) * 8] = v;
    }
    {
      bf16x8_t v = *(const bf16x8_t*)&WqT[(size_t)(n0 + sbc) * DM + kb + sbk * 8];
      *(bf16x8_t*)&Blds[(((sbc >> 4) * 4 + sbk) * 16 + (sbc & 15)) * 8] = v;
    }
    __syncthreads();
    bf16x8_t af = *(const bf16x8_t*)&Alds[((wave * 4 + g) * 16 + lr) * 8];
#pragma unroll
    for (int c = 0; c < 4; ++c) {
      bf16x8_t bfr = *(const bf16x8_t*)&Blds[((c * 4 + g) * 16 + lr) * 8];
      acc[c] = __builtin_amdgcn_mfma_f32_16x16x32_bf16(af, bfr, acc[c], 0, 0, 0);
    }
  }

  const int rowb = m0 + wave * 16 + g * 4;  // rows rowb..rowb+3 (4-aligned)
  if (n0 < 128) {
#pragma unroll
    for (int c = 0; c < 4; ++c) {
      int col = n0 + c * 16 + lr;
      float bv = bias[col];
#pragma unroll
      for (int r = 0; r < 4; ++r)
        qbf[(size_t)(rowb + r) * DA + col] = f2bf(acc[c][r] + bv);
    }
  } else if (n0 < 256) {
    // K packed
#pragma unroll
    for (int c = 0; c < 4; ++c) {
      int col = n0 + c * 16 + lr;
      float bv = bias[col];
      int kd = col - 128, kc = kd >> 3, jj = kd & 7;
#pragma unroll
      for (int r = 0; r < 4; ++r) {
        int row = rowb + r;
        int kt = row >> 6, rl = row & 63;
        int unit = (((rl >> 4) * 4 + (kc >> 2)) * 4 + (kc & 3));
        kpk[(size_t)kt * 8192 + unit * 128 + (rl & 15) * 8 + jj] = f2bf(acc[c][r] + bv);
      }
    }
  } else {
    // V packed: rows rowb..rowb+3 share tile and 8-block; pack 4 along n
    int kt = rowb >> 6, nl0 = rowb & 63;
    int nc = nl0 >> 3, nj0 = nl0 & 7;
    int unitb = ((nc >> 2) * 4 + (nc & 3));
#pragma unroll
    for (int c = 0; c < 4; ++c) {
      int col = n0 + c * 16 + lr;
      float bv = bias[col];
      int d = col - 256;
      union { bf16x4_t v; unsigned short u[4]; } pk;
#pragma unroll
      for (int r = 0; r < 4; ++r) pk.u[r] = f2bf(acc[c][r] + bv);
      int unit = (d >> 4) * 8 + unitb;
      *(bf16x4_t*)&vpk[(size_t)kt * 8192 + unit * 128 + (d & 15) * 8 + nj0] = pk.v;
    }
  }
}

// ---------------------------------------------------------------------------
// Kernel 2: split-KV causal flash attention (partial).
// item = (batch, q-tile of 64 rows, kv-chunk of <=16 tiles of 64 keys).
// Per batch: q-tile t has floor(t/16)+1 chunks -> 160 items; 640 total.
// Writes unnormalized O (bf16) + per-row (m,l) f32.
// ---------------------------------------------------------------------------
__global__ __launch_bounds__(256, 4) void attn_kernel(
    const unsigned short* __restrict__ qbf, const unsigned short* __restrict__ kpk,
    const unsigned short* __restrict__ vpk, unsigned short* __restrict__ part_o,
    float* __restrict__ part_ml) {
  __shared__ unsigned short Klds[64 * 128];
  __shared__ unsigned short Vlds[128 * 64];
  __shared__ unsigned short Plds[4][1024];

  const int item = blockIdx.x;
  const int b = item / IPB;
  const int idx = item - b * IPB;
  int s, j;
  if (idx < 16)      { s = 0; j = idx; }
  else if (idx < 48) { s = 1; j = idx - 16; }
  else if (idx < 96) { s = 2; j = idx - 48; }
  else               { s = 3; j = idx - 96; }
  const int qt = s * 16 + j / (s + 1);
  const int ci = j - (j / (s + 1)) * (s + 1);
  const int nt = (ci == s) ? (qt & 15) + 1 : 16;  // tiles in this chunk

  const int tid = threadIdx.x;
  const int wave = tid >> 6, lane = tid & 63;
  const int g = lane >> 4, lr = lane & 15;
  const float scale = 0.08838834764831845f;  // 1/sqrt(128)

  bf16x8_t qf[4];
  {
    const unsigned short* qb =
        qbf + ((size_t)(b * SEQ + qt * 64 + wave * 16 + lr)) * DA + g * 8;
#pragma unroll
    for (int c = 0; c < 4; ++c) qf[c] = *(const bf16x8_t*)(qb + c * 32);
  }

  f32x4 oacc[8] = {};
  float m_r[4] = {-INFINITY, -INFINITY, -INFINITY, -INFINITY};
  float l_r[4] = {0.f, 0.f, 0.f, 0.f};

  const unsigned short* ksrc =
      kpk + (size_t)(b * 64 + ci * 16) * 8192 + wave * 2048 + lane * 8;
  const unsigned short* vsrc =
      vpk + (size_t)(b * 64 + ci * 16) * 8192 + wave * 2048 + lane * 8;
  char* kdst = (char*)Klds + wave * 4096;
  char* vdst = (char*)Vlds + wave * 4096;

  for (int tt = 0; tt < nt; ++tt) {
    __syncthreads();  // prev compute done before DMA overwrites LDS
#pragma unroll
    for (int i = 0; i < 4; ++i) {
      GLDS16(ksrc + (size_t)tt * 8192 + i * 512, kdst + i * 1024);
      GLDS16(vsrc + (size_t)tt * 8192 + i * 512, vdst + i * 1024);
    }
    __syncthreads();  // implicit vmcnt(0) drain: tile resident

    const bool dg = (ci * 16 + tt) == qt;  // diagonal tile needs mask

    f32x4 sacc[4] = {};
#pragma unroll
    for (int ct = 0; ct < 4; ++ct)
#pragma unroll
      for (int c = 0; c < 4; ++c) {
        bf16x8_t kf = *(const bf16x8_t*)&Klds[(((ct * 4 + c) * 4 + g) * 16 + lr) * 8];
        sacc[ct] = __builtin_amdgcn_mfma_f32_16x16x32_bf16(qf[c], kf, sacc[ct], 0, 0, 0);
      }

    float tmax[4] = {-INFINITY, -INFINITY, -INFINITY, -INFINITY};
#pragma unroll
    for (int ct = 0; ct < 4; ++ct) {
      int kj = ct * 16 + lr;  // key index within tile
#pragma unroll
      for (int r = 0; r < 4; ++r) {
        float sv = sacc[ct][r] * scale;
        if (dg) {
          int qi = wave * 16 + g * 4 + r;  // q row within tile
          sv = (kj <= qi) ? sv : -INFINITY;
        }
        sacc[ct][r] = sv;
        tmax[r] = fmaxf(tmax[r], sv);
      }
    }
#pragma unroll
    for (int msk = 1; msk <= 8; msk <<= 1)
#pragma unroll
      for (int r = 0; r < 4; ++r)
        tmax[r] = fmaxf(tmax[r], __shfl_xor(tmax[r], msk, 64));
    float alpha[4];
#pragma unroll
    for (int r = 0; r < 4; ++r) {
      float mn = fmaxf(m_r[r], tmax[r]);
      alpha[r] = __expf(m_r[r] - mn);
      m_r[r] = mn;
    }
    float rsum[4] = {0.f, 0.f, 0.f, 0.f};
#pragma unroll
    for (int ct = 0; ct < 4; ++ct)
#pragma unroll
      for (int r = 0; r < 4; ++r) {
        float p = __expf(sacc[ct][r] - m_r[r]);
        sacc[ct][r] = p;
        rsum[r] += p;
      }
#pragma unroll
    for (int msk = 1; msk <= 8; msk <<= 1)
#pragma unroll
      for (int r = 0; r < 4; ++r) rsum[r] += __shfl_xor(rsum[r], msk, 64);
#pragma unroll
    for (int r = 0; r < 4; ++r) l_r[r] = l_r[r] * alpha[r] + rsum[r];
#pragma unroll
    for (int t = 0; t < 8; ++t)
#pragma unroll
      for (int r = 0; r < 4; ++r) oacc[t][r] *= alpha[r];

    // P -> per-wave LDS, conflict-minimized unit map: unit = q*8 + (kk ^ (g<<1))
    unsigned short* pw = Plds[wave];
    const int e = lr >> 3, jj = lr & 7;
#pragma unroll
    for (int ct = 0; ct < 4; ++ct)
#pragma unroll
      for (int r = 0; r < 4; ++r) {
        int unit = (g * 4 + r) * 8 + ((2 * ct + e) ^ (g << 1));
        pw[unit * 8 + jj] = f2bf(sacc[ct][r]);
      }
    asm volatile("s_waitcnt lgkmcnt(0)" ::: "memory");
    __builtin_amdgcn_sched_barrier(0);
    bf16x8_t pf[2];
#pragma unroll
    for (int c = 0; c < 2; ++c) {
      int unit = lr * 8 + ((c * 4 + g) ^ ((lr >> 2) << 1));
      pf[c] = *(const bf16x8_t*)&pw[unit * 8];
    }
#pragma unroll
    for (int t = 0; t < 8; ++t)
#pragma unroll
      for (int c = 0; c < 2; ++c) {
        bf16x8_t vf = *(const bf16x8_t*)&Vlds[(((t * 2 + c) * 4 + g) * 16 + lr) * 8];
        oacc[t] = __builtin_amdgcn_mfma_f32_16x16x32_bf16(pf[c], vf, oacc[t], 0, 0, 0);
      }
  }

  // epilogue: unnormalized partials
  const size_t ob = (size_t)item * 8192;
#pragma unroll
  for (int r = 0; r < 4; ++r) {
    int rowl = wave * 16 + g * 4 + r;
#pragma unroll
    for (int t = 0; t < 8; ++t)
      part_o[ob + rowl * 128 + t * 16 + lr] = f2bf(oacc[t][r]);
    if (lr == 0) {
      part_ml[((size_t)item * 64 + rowl) * 2 + 0] = m_r[r];
      part_ml[((size_t)item * 64 + rowl) * 2 + 1] = l_r[r];
    }
  }
}

// ---------------------------------------------------------------------------
// Kernel 2b: combine partials -> ctx (bf16), applying key_mask and 1/l.
// One block per 64-row q-tile; thread = row*4 + colgroup(32 cols).
// ---------------------------------------------------------------------------
__global__ __launch_bounds__(256) void combine_kernel(
    const unsigned short* __restrict__ part_o, const float* __restrict__ part_ml,
    const float* __restrict__ key_mask, unsigned short* __restrict__ ctx) {
  const int gqt = blockIdx.x;            // 0..255
  const int b = gqt >> 6, qt = gqt & 63;
  const int s = qt >> 4, nc = s + 1;
  const int base = (s == 0) ? 0 : (s == 1) ? 16 : (s == 2) ? 48 : 96;
  const int idx0 = base + (qt - s * 16) * nc;
  const int row = threadIdx.x >> 2, cg = threadIdx.x & 3;

  float m = -INFINITY;
  for (int ci = 0; ci < nc; ++ci) {
    int item = b * IPB + idx0 + ci;
    m = fmaxf(m, part_ml[((size_t)item * 64 + row) * 2 + 0]);
  }
  float l = 0.f;
  float acc[32];
#pragma unroll
  for (int k = 0; k < 32; ++k) acc[k] = 0.f;
  for (int ci = 0; ci < nc; ++ci) {
    int item = b * IPB + idx0 + ci;
    float mi = part_ml[((size_t)item * 64 + row) * 2 + 0];
    float li = part_ml[((size_t)item * 64 + row) * 2 + 1];
    float w = __expf(mi - m);
    l += w * li;
    const unsigned short* po = part_o + (size_t)item * 8192 + row * 128 + cg * 32;
#pragma unroll
    for (int k8 = 0; k8 < 4; ++k8) {
      bf16x8_t v = *(const bf16x8_t*)(po + k8 * 8);
#pragma unroll
      for (int jj = 0; jj < 8; ++jj)
        acc[k8 * 8 + jj] += w * bf2f((unsigned short)v[jj]);
    }
  }
  int rowg = gqt * 64 + row;
  float sc = key_mask[rowg] / l;
  unsigned short* co = ctx + (size_t)rowg * 128 + cg * 32;
#pragma unroll
  for (int k8 = 0; k8 < 4; ++k8) {
    union { bf16x8_t v; unsigned short u[8]; } pk;
#pragma unroll
    for (int jj = 0; jj < 8; ++jj) pk.u[jj] = f2bf(acc[k8 * 8 + jj] * sc);
    *(bf16x8_t*)(co + k8 * 8) = pk.v;
  }
}

// ---------------------------------------------------------------------------
// Kernel 3: output projection.  [16384,128] @ [128,512] + bias -> fp32 out
// ---------------------------------------------------------------------------
__global__ __launch_bounds__(256) void outproj_kernel(
    const unsigned short* __restrict__ ctx, const unsigned short* __restrict__ WoT,
    const float* __restrict__ bias, float* __restrict__ out) {
  __shared__ unsigned short Alds[64 * 32];
  __shared__ unsigned short Blds[64 * 32];

  const int m0 = blockIdx.x * 64;
  const int n0 = blockIdx.y * 64;
  const int tid = threadIdx.x;
  const int wave = tid >> 6, lane = tid & 63;
  const int g = lane >> 4, lr = lane & 15;
  const int sar = tid >> 2, sak = tid & 3;
  const int sbc = tid & 63, sbk = tid >> 6;

  f32x4 acc[4] = {};

  for (int kb = 0; kb < DA; kb += 32) {
    __syncthreads();
    {
      bf16x8_t v = *(const bf16x8_t*)&ctx[(size_t)(m0 + sar) * DA + kb + sak * 8];
      *(bf16x8_t*)&Alds[(((sar >> 4) * 4 + sak) * 16 + (sar & 15)) * 8] = v;
    }
    {
      bf16x8_t v = *(const bf16x8_t*)&WoT[(size_t)(n0 + sbc) * DA + kb + sbk * 8];
      *(bf16x8_t*)&Blds[(((sbc >> 4) * 4 + sbk) * 16 + (sbc & 15)) * 8] = v;
    }
    __syncthreads();
    bf16x8_t af = *(const bf16x8_t*)&Alds[((wave * 4 + g) * 16 + lr) * 8];
#pragma unroll
    for (int c = 0; c < 4; ++c) {
      bf16x8_t bfr = *(const bf16x8_t*)&Blds[((c * 4 + g) * 16 + lr) * 8];
      acc[c] = __builtin_amdgcn_mfma_f32_16x16x32_bf16(af, bfr, acc[c], 0, 0, 0);
    }
  }

  const int rowb = m0 + wave * 16 + g * 4;
#pragma unroll
  for (int c = 0; c < 4; ++c) {
    int col = n0 + c * 16 + lr;
    float bv = bias[col];
#pragma unroll
    for (int r = 0; r < 4; ++r)
      out[(size_t)(rowb + r) * DM + col] = acc[c][r] + bv;
  }
}

// ---------------------------------------------------------------------------
extern "C" void kernel_launch(void* const* d_in, const int* in_sizes, int n_in,
                              void* d_out, int out_size, void* d_ws, size_t ws_size,
                              hipStream_t stream) {
  const float* x = (const float*)d_in[0];
  const float* key_mask = (const float*)d_in[1];
  const float* W_qkv = (const float*)d_in[2];
  const float* b_qkv = (const float*)d_in[3];
  const float* W_out = (const float*)d_in[4];
  const float* b_out = (const float*)d_in[5];
  float* out = (float*)d_out;

  unsigned short* ws = (unsigned short*)d_ws;
  unsigned short* qbf = ws;                        // [BN][128] bf16
  unsigned short* kpk = qbf + (size_t)BN * DA;     // packed K tiles
  unsigned short* vpk = kpk + (size_t)BN * DA;     // packed V tiles
  unsigned short* ctx = vpk + (size_t)BN * DA;     // [BN][128] bf16
  unsigned short* xbf = ctx + (size_t)BN * DA;     // [BN][512] bf16 (dead after qkv)
  unsigned short* WqT = xbf + (size_t)BN * DM;     // [384][512]
  unsigned short* WoT = WqT + (size_t)384 * 512;   // [512][128]

  // reuse xbf region for attention partials (10.8 MB < 16.8 MB)
  unsigned short* part_o = xbf;                    // [640][64][128] bf16
  float* part_ml = (float*)(xbf + (size_t)N_ITEMS * 8192);  // [640][64][2] f32

  prep_kernel<<<dim3((BN * DM / 8 + 255) / 256), 256, 0, stream>>>(
      x, W_qkv, W_out, xbf, WqT, WoT);
  qkv_kernel<<<dim3(BN / 64, 6), 256, 0, stream>>>(xbf, WqT, b_qkv, qbf, kpk, vpk);
  attn_kernel<<<dim3(N_ITEMS), 256, 0, stream>>>(qbf, kpk, vpk, part_o, part_ml);
  combine_kernel<<<dim3(BN / 64), 256, 0, stream>>>(part_o, part_ml, key_mask, ctx);
  outproj_kernel<<<dim3(BN / 64, 8), 256, 0, stream>>>(ctx, WoT, b_out, out);
}

// Round 3
// 106.192 us; speedup vs baseline: 2.1113x; 1.0606x over previous
//
#include <hip/hip_runtime.h>
#include <hip/hip_bf16.h>
#include <math.h>

typedef __attribute__((ext_vector_type(4))) float f32x4;
typedef __attribute__((ext_vector_type(4))) float fvec4;
typedef __attribute__((ext_vector_type(8))) short bf16x8_t;
typedef __attribute__((ext_vector_type(4))) short bf16x4_t;

static constexpr int BATCH = 4;
static constexpr int SEQ = 4096;
static constexpr int DM = 512;
static constexpr int DA = 128;
static constexpr int BN = BATCH * SEQ;  // 16384
static constexpr int IPB = 160;         // split-KV items per batch
static constexpr int N_ITEMS = BATCH * IPB;  // 640

static __device__ __forceinline__ unsigned short f2bf(float f) {
  unsigned u = __builtin_bit_cast(unsigned, f);
  u += 0x7fffu + ((u >> 16) & 1u);
  return (unsigned short)(u >> 16);
}
static __device__ __forceinline__ float bf2f(unsigned short u) {
  return __builtin_bit_cast(float, ((unsigned)u) << 16);
}
static __device__ __forceinline__ float fexp2(float x) {
#if __has_builtin(__builtin_amdgcn_exp2f)
  return __builtin_amdgcn_exp2f(x);
#else
  return exp2f(x);
#endif
}
// packed f32x2 -> bf16x2 (RNE), dst.lo = lo, dst.hi = hi
static __device__ __forceinline__ unsigned pkbf(float lo, float hi) {
  unsigned r;
  asm("v_cvt_pk_bf16_f32 %0, %1, %2" : "=v"(r) : "v"(lo), "v"(hi));
  return r;
}

#define GLDS16(gsrc, ldst)                                                        \
  __builtin_amdgcn_global_load_lds(                                               \
      (const __attribute__((address_space(1))) void*)(gsrc),                      \
      (__attribute__((address_space(3))) void*)(ldst), 16, 0, 0)

// scale * log2(e): folded into Q at qkv epilogue
static constexpr float QSC = 0.08838834764831845f * 1.4426950408889634f;

// ---------------------------------------------------------------------------
// Kernel 0: cast x -> bf16, transpose+cast W_qkv -> [384][512], W_out -> [512][128]
// ---------------------------------------------------------------------------
__global__ __launch_bounds__(256) void prep_kernel(
    const float* __restrict__ x, const float* __restrict__ Wqkv,
    const float* __restrict__ Wout, unsigned short* __restrict__ xbf,
    unsigned short* __restrict__ WqT, unsigned short* __restrict__ WoT) {
  long long i = ((long long)blockIdx.x * 256 + threadIdx.x) * 8;
  if (i < (long long)BN * DM) {
    fvec4 a = *(const fvec4*)&x[i];
    fvec4 b = *(const fvec4*)&x[i + 4];
    union { bf16x8_t v; unsigned short u[8]; } pk;
    pk.u[0] = f2bf(a[0]); pk.u[1] = f2bf(a[1]); pk.u[2] = f2bf(a[2]); pk.u[3] = f2bf(a[3]);
    pk.u[4] = f2bf(b[0]); pk.u[5] = f2bf(b[1]); pk.u[6] = f2bf(b[2]); pk.u[7] = f2bf(b[3]);
    *(bf16x8_t*)&xbf[i] = pk.v;
  }
  int t = blockIdx.x * 256 + threadIdx.x;
  if (t < 512 * 384) {
    int k = t / 384, n = t - k * 384;
    WqT[n * 512 + k] = f2bf(Wqkv[t]);
  }
  if (t < 128 * 512) {
    int k = t >> 9, n = t & 511;
    WoT[n * 128 + k] = f2bf(Wout[t]);
  }
}

// ---------------------------------------------------------------------------
// Kernel 1: QKV projection.  [16384,512] @ [512,384] + bias.
// q: bf16 row-major [BN][128], PRE-SCALED by QSC (= 1/sqrt(d) * log2e).
// k: packed per-64-row-tile, fragment-major unit order (linear copy -> LDS).
// v: packed per-64-row-tile with sigma-permuted key index so PV B-frags are
//    built in-register from cvt_pk with zero shuffles:
//    sigma(32c+8g+j) = 32c + 16*(j>>2) + 4g + (j&3)
// ---------------------------------------------------------------------------
__global__ __launch_bounds__(256) void qkv_kernel(
    const unsigned short* __restrict__ xbf, const unsigned short* __restrict__ WqT,
    const float* __restrict__ bias, unsigned short* __restrict__ qbf,
    unsigned short* __restrict__ kpk, unsigned short* __restrict__ vpk) {
  __shared__ unsigned short Alds[64 * 32];
  __shared__ unsigned short Blds[64 * 32];

  const int m0 = blockIdx.x * 64;
  const int n0 = blockIdx.y * 64;
  const int tid = threadIdx.x;
  const int wave = tid >> 6, lane = tid & 63;
  const int g = lane >> 4, lr = lane & 15;
  const int sar = tid >> 2, sak = tid & 3;
  const int sbc = tid & 63, sbk = tid >> 6;

  f32x4 acc[4] = {};

  for (int kb = 0; kb < DM; kb += 32) {
    __syncthreads();
    {
      bf16x8_t v = *(const bf16x8_t*)&xbf[(size_t)(m0 + sar) * DM + kb + sak * 8];
      *(bf16x8_t*)&Alds[(((sar >> 4) * 4 + sak) * 16 + (sar & 15)) * 8] = v;
    }
    {
      bf16x8_t v = *(const bf16x8_t*)&WqT[(size_t)(n0 + sbc) * DM + kb + sbk * 8];
      *(bf16x8_t*)&Blds[(((sbc >> 4) * 4 + sbk) * 16 + (sbc & 15)) * 8] = v;
    }
    __syncthreads();
    bf16x8_t af = *(const bf16x8_t*)&Alds[((wave * 4 + g) * 16 + lr) * 8];
#pragma unroll
    for (int c = 0; c < 4; ++c) {
      bf16x8_t bfr = *(const bf16x8_t*)&Blds[((c * 4 + g) * 16 + lr) * 8];
      acc[c] = __builtin_amdgcn_mfma_f32_16x16x32_bf16(af, bfr, acc[c], 0, 0, 0);
    }
  }

  const int rowb = m0 + wave * 16 + g * 4;  // rows rowb..rowb+3 (4-aligned)
  if (n0 < 128) {
#pragma unroll
    for (int c = 0; c < 4; ++c) {
      int col = n0 + c * 16 + lr;
      float bv = bias[col];
#pragma unroll
      for (int r = 0; r < 4; ++r)
        qbf[(size_t)(rowb + r) * DA + col] = f2bf((acc[c][r] + bv) * QSC);
    }
  } else if (n0 < 256) {
    // K packed (fragment-major, linear-copy friendly)
#pragma unroll
    for (int c = 0; c < 4; ++c) {
      int col = n0 + c * 16 + lr;
      float bv = bias[col];
      int kd = col - 128, kc = kd >> 3, jj = kd & 7;
#pragma unroll
      for (int r = 0; r < 4; ++r) {
        int row = rowb + r;
        int kt = row >> 6, rl = row & 63;
        int unit = (((rl >> 4) * 4 + (kc >> 2)) * 4 + (kc & 3));
        kpk[(size_t)kt * 8192 + unit * 128 + (rl & 15) * 8 + jj] = f2bf(acc[c][r] + bv);
      }
    }
  } else {
    // V packed with sigma-permuted key index
    int kt = rowb >> 6, nl0 = rowb & 63;
    int cp = nl0 >> 5, gp = (nl0 >> 2) & 3, j2 = (nl0 >> 4) & 1;
    int ebase = j2 * 4;
#pragma unroll
    for (int c = 0; c < 4; ++c) {
      int col = n0 + c * 16 + lr;
      float bv = bias[col];
      int d = col - 256;
      union { bf16x4_t v; unsigned short u[4]; } pk;
#pragma unroll
      for (int r = 0; r < 4; ++r) pk.u[r] = f2bf(acc[c][r] + bv);
      int unit = (d >> 4) * 8 + cp * 4 + gp;
      *(bf16x4_t*)&vpk[(size_t)kt * 8192 + unit * 128 + (d & 15) * 8 + ebase] = pk.v;
    }
  }
}

// ---------------------------------------------------------------------------
// Kernel 2: split-KV causal flash attention, swapped-QK (S^T) form, pipelined.
// item = (batch, 64-row q-tile, kv-chunk of <=16 64-key tiles).
// Double-buffered K/V LDS; counted vmcnt(8); raw s_barrier; defer-max.
// Lane (g,lr) of wave w owns q-row = qt*64 + w*16 + lr.
// sacc[ct][r] = S^T[key=16ct+4g+r][q=lr]  (in log2-domain: Q pre-scaled).
// ---------------------------------------------------------------------------
__global__ __launch_bounds__(256) void attn_kernel(
    const unsigned short* __restrict__ qbf, const unsigned short* __restrict__ kpk,
    const unsigned short* __restrict__ vpk, const float* __restrict__ key_mask,
    unsigned short* __restrict__ part_o, float* __restrict__ part_ml,
    unsigned short* __restrict__ ctx) {
  __shared__ unsigned short Klds[2][8192];
  __shared__ unsigned short Vlds[2][8192];

  // LPT-ish dispatch: reversed idx so long chunks launch first
  const int flat = blockIdx.x;
  const int b = flat & 3;
  const int idx = IPB - 1 - (flat >> 2);
  int s, j;
  if (idx < 16)      { s = 0; j = idx; }
  else if (idx < 48) { s = 1; j = idx - 16; }
  else if (idx < 96) { s = 2; j = idx - 48; }
  else               { s = 3; j = idx - 96; }
  const int qt = s * 16 + j / (s + 1);
  const int ci = j - (j / (s + 1)) * (s + 1);
  const int nt = (ci == s) ? (qt & 15) + 1 : 16;  // tiles in this chunk
  const bool direct = (qt < 16);                  // single-chunk item

  const int tid = threadIdx.x;
  const int wave = tid >> 6, lane = tid & 63;
  const int g = lane >> 4, lr = lane & 15;
  const int qloc = wave * 16 + lr;  // q row within the 64-row tile

  bf16x8_t qf[4];
  {
    const unsigned short* qb =
        qbf + ((size_t)(b * SEQ + qt * 64 + qloc)) * DA + g * 8;
#pragma unroll
    for (int c = 0; c < 4; ++c) qf[c] = *(const bf16x8_t*)(qb + c * 32);
  }

  f32x4 oacc[8] = {};
  float m_r = -INFINITY, l_r = 0.f;

  const unsigned short* ksrc =
      kpk + (size_t)(b * 64 + ci * 16) * 8192 + wave * 2048 + lane * 8;
  const unsigned short* vsrc =
      vpk + (size_t)(b * 64 + ci * 16) * 8192 + wave * 2048 + lane * 8;

#define STAGE(buf, tt)                                                       \
  do {                                                                       \
    char* kdst_ = (char*)Klds[buf] + wave * 4096;                            \
    char* vdst_ = (char*)Vlds[buf] + wave * 4096;                            \
    _Pragma("unroll")                                                        \
    for (int i_ = 0; i_ < 4; ++i_) {                                         \
      GLDS16(ksrc + (size_t)(tt) * 8192 + i_ * 512, kdst_ + i_ * 1024);      \
      GLDS16(vsrc + (size_t)(tt) * 8192 + i_ * 512, vdst_ + i_ * 1024);      \
    }                                                                        \
  } while (0)

  STAGE(0, 0);  // prologue

  for (int tt = 0; tt < nt; ++tt) {
    const int cur = tt & 1;
    if (tt + 1 < nt) {
      STAGE(cur ^ 1, tt + 1);
      asm volatile("s_waitcnt vmcnt(8)" ::: "memory");  // drain cur's loads only
    } else {
      asm volatile("s_waitcnt vmcnt(0)" ::: "memory");
    }
    __builtin_amdgcn_s_barrier();
    __builtin_amdgcn_sched_barrier(0);

    // ---- QK^T (swapped): sacc[ct] = S^T tile ----
    f32x4 sacc[4] = {};
    __builtin_amdgcn_s_setprio(1);
#pragma unroll
    for (int ct = 0; ct < 4; ++ct)
#pragma unroll
      for (int c = 0; c < 4; ++c) {
        bf16x8_t kf = *(const bf16x8_t*)&Klds[cur][(((ct * 4 + c) * 4 + g) * 16 + lr) * 8];
        sacc[ct] = __builtin_amdgcn_mfma_f32_16x16x32_bf16(kf, qf[c], sacc[ct], 0, 0, 0);
      }
    __builtin_amdgcn_s_setprio(0);

    // ---- causal mask (diagonal tile only) ----
    if ((ci * 16 + tt) == qt) {
#pragma unroll
      for (int ct = 0; ct < 4; ++ct)
#pragma unroll
        for (int r = 0; r < 4; ++r) {
          int key = ct * 16 + 4 * g + r;
          if (key > qloc) sacc[ct][r] = -INFINITY;
        }
    }

    // ---- online softmax (log2 domain), in-lane row reduce ----
    float tmax = -INFINITY;
#pragma unroll
    for (int ct = 0; ct < 4; ++ct)
#pragma unroll
      for (int r = 0; r < 4; ++r) tmax = fmaxf(tmax, sacc[ct][r]);
    tmax = fmaxf(tmax, __shfl_xor(tmax, 16, 64));
    tmax = fmaxf(tmax, __shfl_xor(tmax, 32, 64));

    if (!__all(tmax <= m_r + 10.0f)) {  // defer-max: rescale only on real growth
      float mn = fmaxf(m_r, tmax);
      float al = fexp2(m_r - mn);
      m_r = mn;
      l_r *= al;
#pragma unroll
      for (int t = 0; t < 8; ++t)
#pragma unroll
        for (int r = 0; r < 4; ++r) oacc[t][r] *= al;
    }

    float rs = 0.f;
#pragma unroll
    for (int ct = 0; ct < 4; ++ct)
#pragma unroll
      for (int r = 0; r < 4; ++r) {
        float p = fexp2(sacc[ct][r] - m_r);
        sacc[ct][r] = p;
        rs += p;
      }
    rs += __shfl_xor(rs, 16, 64);
    rs += __shfl_xor(rs, 32, 64);
    l_r += rs;

    // ---- P B-frags directly from registers (sigma-permuted V) ----
    bf16x8_t pb[2];
#pragma unroll
    for (int c = 0; c < 2; ++c) {
      union { unsigned u[4]; bf16x8_t v; } pk;
      pk.u[0] = pkbf(sacc[2 * c][0], sacc[2 * c][1]);
      pk.u[1] = pkbf(sacc[2 * c][2], sacc[2 * c][3]);
      pk.u[2] = pkbf(sacc[2 * c + 1][0], sacc[2 * c + 1][1]);
      pk.u[3] = pkbf(sacc[2 * c + 1][2], sacc[2 * c + 1][3]);
      pb[c] = pk.v;
    }

    // ---- PV: O^T accumulate ----
    __builtin_amdgcn_s_setprio(1);
#pragma unroll
    for (int t = 0; t < 8; ++t)
#pragma unroll
      for (int c = 0; c < 2; ++c) {
        bf16x8_t vf = *(const bf16x8_t*)&Vlds[cur][(((t * 2 + c) * 4 + g) * 16 + lr) * 8];
        oacc[t] = __builtin_amdgcn_mfma_f32_16x16x32_bf16(vf, pb[c], oacc[t], 0, 0, 0);
      }
    __builtin_amdgcn_s_setprio(0);

    __builtin_amdgcn_s_barrier();  // protect buf[cur] before next STAGE
  }
#undef STAGE

  // ---- epilogue: lane owns q-row = qloc, d = 16t + 4g + r ----
  const int row = qloc;
  if (direct) {
    float km = key_mask[b * SEQ + qt * 64 + row];
    float inv = km / l_r;
    unsigned short* co = ctx + ((size_t)(b * SEQ + qt * 64 + row)) * DA;
#pragma unroll
    for (int t = 0; t < 8; ++t) {
      union { bf16x4_t v; unsigned short u[4]; } pk;
#pragma unroll
      for (int r = 0; r < 4; ++r) pk.u[r] = f2bf(oacc[t][r] * inv);
      *(bf16x4_t*)&co[t * 16 + 4 * g] = pk.v;
    }
  } else {
    const int slot = b * IPB + idx;
    unsigned short* po = part_o + (size_t)slot * 8192 + row * 128;
#pragma unroll
    for (int t = 0; t < 8; ++t) {
      union { bf16x4_t v; unsigned short u[4]; } pk;
#pragma unroll
      for (int r = 0; r < 4; ++r) pk.u[r] = f2bf(oacc[t][r]);
      *(bf16x4_t*)&po[t * 16 + 4 * g] = pk.v;
    }
    if (g == 0) {
      float2 ml = make_float2(m_r, l_r);
      *(float2*)&part_ml[((size_t)slot * 64 + row) * 2] = ml;
    }
  }
}

// ---------------------------------------------------------------------------
// Kernel 2b: combine partials -> ctx for qt >= 16 (multi-chunk items).
// grid (48, 4): qt = 16 + bx, b = by.
// ---------------------------------------------------------------------------
__global__ __launch_bounds__(256) void combine_kernel(
    const unsigned short* __restrict__ part_o, const float* __restrict__ part_ml,
    const float* __restrict__ key_mask, unsigned short* __restrict__ ctx) {
  const int qt = 16 + blockIdx.x;
  const int b = blockIdx.y;
  const int s = qt >> 4, nc = s + 1;
  const int base = (s == 1) ? 16 : (s == 2) ? 48 : 96;
  const int idx0 = base + (qt - s * 16) * nc;
  const int row = threadIdx.x >> 2, cg = threadIdx.x & 3;

  float m = -INFINITY;
  for (int ci = 0; ci < nc; ++ci) {
    int item = b * IPB + idx0 + ci;
    m = fmaxf(m, part_ml[((size_t)item * 64 + row) * 2 + 0]);
  }
  float l = 0.f;
  float acc[32];
#pragma unroll
  for (int k = 0; k < 32; ++k) acc[k] = 0.f;
  for (int ci = 0; ci < nc; ++ci) {
    int item = b * IPB + idx0 + ci;
    float mi = part_ml[((size_t)item * 64 + row) * 2 + 0];
    float li = part_ml[((size_t)item * 64 + row) * 2 + 1];
    float w = fexp2(mi - m);
    l += w * li;
    const unsigned short* po = part_o + (size_t)item * 8192 + row * 128 + cg * 32;
#pragma unroll
    for (int k8 = 0; k8 < 4; ++k8) {
      bf16x8_t v = *(const bf16x8_t*)(po + k8 * 8);
#pragma unroll
      for (int jj = 0; jj < 8; ++jj)
        acc[k8 * 8 + jj] += w * bf2f((unsigned short)v[jj]);
    }
  }
  int rowg = (b * 64 + qt) * 64 + row;
  float sc = key_mask[rowg] / l;
  unsigned short* co = ctx + (size_t)rowg * 128 + cg * 32;
#pragma unroll
  for (int k8 = 0; k8 < 4; ++k8) {
    union { bf16x8_t v; unsigned short u[8]; } pk;
#pragma unroll
    for (int jj = 0; jj < 8; ++jj) pk.u[jj] = f2bf(acc[k8 * 8 + jj] * sc);
    *(bf16x8_t*)(co + k8 * 8) = pk.v;
  }
}

// ---------------------------------------------------------------------------
// Kernel 3: output projection.  [16384,128] @ [128,512] + bias -> fp32 out
// ---------------------------------------------------------------------------
__global__ __launch_bounds__(256) void outproj_kernel(
    const unsigned short* __restrict__ ctx, const unsigned short* __restrict__ WoT,
    const float* __restrict__ bias, float* __restrict__ out) {
  __shared__ unsigned short Alds[64 * 32];
  __shared__ unsigned short Blds[64 * 32];

  const int m0 = blockIdx.x * 64;
  const int n0 = blockIdx.y * 64;
  const int tid = threadIdx.x;
  const int wave = tid >> 6, lane = tid & 63;
  const int g = lane >> 4, lr = lane & 15;
  const int sar = tid >> 2, sak = tid & 3;
  const int sbc = tid & 63, sbk = tid >> 6;

  f32x4 acc[4] = {};

  for (int kb = 0; kb < DA; kb += 32) {
    __syncthreads();
    {
      bf16x8_t v = *(const bf16x8_t*)&ctx[(size_t)(m0 + sar) * DA + kb + sak * 8];
      *(bf16x8_t*)&Alds[(((sar >> 4) * 4 + sak) * 16 + (sar & 15)) * 8] = v;
    }
    {
      bf16x8_t v = *(const bf16x8_t*)&WoT[(size_t)(n0 + sbc) * DA + kb + sbk * 8];
      *(bf16x8_t*)&Blds[(((sbc >> 4) * 4 + sbk) * 16 + (sbc & 15)) * 8] = v;
    }
    __syncthreads();
    bf16x8_t af = *(const bf16x8_t*)&Alds[((wave * 4 + g) * 16 + lr) * 8];
#pragma unroll
    for (int c = 0; c < 4; ++c) {
      bf16x8_t bfr = *(const bf16x8_t*)&Blds[((c * 4 + g) * 16 + lr) * 8];
      acc[c] = __builtin_amdgcn_mfma_f32_16x16x32_bf16(af, bfr, acc[c], 0, 0, 0);
    }
  }

  const int rowb = m0 + wave * 16 + g * 4;
#pragma unroll
  for (int c = 0; c < 4; ++c) {
    int col = n0 + c * 16 + lr;
    float bv = bias[col];
#pragma unroll
    for (int r = 0; r < 4; ++r)
      out[(size_t)(rowb + r) * DM + col] = acc[c][r] + bv;
  }
}

// ---------------------------------------------------------------------------
extern "C" void kernel_launch(void* const* d_in, const int* in_sizes, int n_in,
                              void* d_out, int out_size, void* d_ws, size_t ws_size,
                              hipStream_t stream) {
  const float* x = (const float*)d_in[0];
  const float* key_mask = (const float*)d_in[1];
  const float* W_qkv = (const float*)d_in[2];
  const float* b_qkv = (const float*)d_in[3];
  const float* W_out = (const float*)d_in[4];
  const float* b_out = (const float*)d_in[5];
  float* out = (float*)d_out;

  unsigned short* ws = (unsigned short*)d_ws;
  unsigned short* qbf = ws;                        // [BN][128] bf16 (pre-scaled)
  unsigned short* kpk = qbf + (size_t)BN * DA;     // packed K tiles
  unsigned short* vpk = kpk + (size_t)BN * DA;     // packed V tiles (sigma-perm)
  unsigned short* ctx = vpk + (size_t)BN * DA;     // [BN][128] bf16
  unsigned short* xbf = ctx + (size_t)BN * DA;     // [BN][512] bf16 (dead after qkv)
  unsigned short* WqT = xbf + (size_t)BN * DM;     // [384][512]
  unsigned short* WoT = WqT + (size_t)384 * 512;   // [512][128]

  // reuse xbf region for attention partials (10.8 MB < 16.8 MB)
  unsigned short* part_o = xbf;                    // [640][64][128] bf16
  float* part_ml = (float*)(xbf + (size_t)N_ITEMS * 8192);  // [640][64][2] f32

  prep_kernel<<<dim3((BN * DM / 8 + 255) / 256), 256, 0, stream>>>(
      x, W_qkv, W_out, xbf, WqT, WoT);
  qkv_kernel<<<dim3(BN / 64, 6), 256, 0, stream>>>(xbf, WqT, b_qkv, qbf, kpk, vpk);
  attn_kernel<<<dim3(N_ITEMS), 256, 0, stream>>>(qbf, kpk, vpk, key_mask,
                                                 part_o, part_ml, ctx);
  combine_kernel<<<dim3(48, 4), 256, 0, stream>>>(part_o, part_ml, key_mask, ctx);
  outproj_kernel<<<dim3(BN / 64, 8), 256, 0, stream>>>(ctx, WoT, b_out, out);
}

// Round 4
// 83.659 us; speedup vs baseline: 2.6800x; 1.2693x over previous
//
#include <hip/hip_runtime.h>
#include <hip/hip_bf16.h>
#include <math.h>

typedef __attribute__((ext_vector_type(4))) float f32x4;
typedef __attribute__((ext_vector_type(4))) float fvec4;
typedef __attribute__((ext_vector_type(8))) short bf16x8_t;
typedef __attribute__((ext_vector_type(4))) short bf16x4_t;

static constexpr int BATCH = 4;
static constexpr int SEQ = 4096;
static constexpr int DM = 512;
static constexpr int DA = 128;
static constexpr int BN = BATCH * SEQ;  // 16384
// split-KV: chunk = 640 keys = 20 tiles of 32 keys
static constexpr int IPB = 238;              // sum over qt of ceil((qt+1)/10)
static constexpr int N_ITEMS = BATCH * IPB;  // 952

static __device__ __forceinline__ unsigned short f2bf(float f) {
  unsigned u = __builtin_bit_cast(unsigned, f);
  u += 0x7fffu + ((u >> 16) & 1u);
  return (unsigned short)(u >> 16);
}
static __device__ __forceinline__ float bf2f(unsigned short u) {
  return __builtin_bit_cast(float, ((unsigned)u) << 16);
}
static __device__ __forceinline__ float fexp2(float x) {
#if __has_builtin(__builtin_amdgcn_exp2f)
  return __builtin_amdgcn_exp2f(x);
#else
  return exp2f(x);
#endif
}
static __device__ __forceinline__ unsigned pkbf(float lo, float hi) {
  unsigned r;
  asm("v_cvt_pk_bf16_f32 %0, %1, %2" : "=v"(r) : "v"(lo), "v"(hi));
  return r;
}

#define GLDS16(gsrc, ldst)                                                        \
  __builtin_amdgcn_global_load_lds(                                               \
      (const __attribute__((address_space(1))) void*)(gsrc),                      \
      (__attribute__((address_space(3))) void*)(ldst), 16, 0, 0)

// scale * log2(e): folded into Q at qkv epilogue
static constexpr float QSC = 0.08838834764831845f * 1.4426950408889634f;

// ---------------------------------------------------------------------------
// Kernel 0: cast x -> bf16, transpose+cast W_qkv -> [384][512], W_out -> [512][128]
// ---------------------------------------------------------------------------
__global__ __launch_bounds__(256) void prep_kernel(
    const float* __restrict__ x, const float* __restrict__ Wqkv,
    const float* __restrict__ Wout, unsigned short* __restrict__ xbf,
    unsigned short* __restrict__ WqT, unsigned short* __restrict__ WoT) {
  long long i = ((long long)blockIdx.x * 256 + threadIdx.x) * 8;
  if (i < (long long)BN * DM) {
    fvec4 a = *(const fvec4*)&x[i];
    fvec4 b = *(const fvec4*)&x[i + 4];
    union { bf16x8_t v; unsigned short u[8]; } pk;
    pk.u[0] = f2bf(a[0]); pk.u[1] = f2bf(a[1]); pk.u[2] = f2bf(a[2]); pk.u[3] = f2bf(a[3]);
    pk.u[4] = f2bf(b[0]); pk.u[5] = f2bf(b[1]); pk.u[6] = f2bf(b[2]); pk.u[7] = f2bf(b[3]);
    *(bf16x8_t*)&xbf[i] = pk.v;
  }
  int t = blockIdx.x * 256 + threadIdx.x;
  if (t < 512 * 384) {
    int k = t / 384, n = t - k * 384;
    WqT[n * 512 + k] = f2bf(Wqkv[t]);
  }
  if (t < 128 * 512) {
    int k = t >> 9, n = t & 511;
    WoT[n * 128 + k] = f2bf(Wout[t]);
  }
}

// ---------------------------------------------------------------------------
// Kernel 1: QKV projection, 128x128 tile, 8 waves, BK=64, global_load_lds with
// pre-swizzled source (16B-slot ^= row&7) -> conflict-free swizzled ds_reads.
// q: bf16 row-major [BN][128], pre-scaled by QSC.
// k: packed 32-key tiles: kpk[tile32][unit=ct*16+c*4+g][pos=token&15][8]
//    (ct=(token>>4)&1, c=d>>5, g=(d>>3)&3, elem=d&7)
// v: packed 32-key tiles, sigma-permuted keys: unit=(d>>4)*4+g', pos=d&15,
//    elem j where key&31 = 16*(j>>2)+4*g'+(j&3)
// ---------------------------------------------------------------------------
__global__ __launch_bounds__(512, 4) void qkv_kernel(
    const unsigned short* __restrict__ xbf, const unsigned short* __restrict__ WqT,
    const float* __restrict__ bias, unsigned short* __restrict__ qbf,
    unsigned short* __restrict__ kpk, unsigned short* __restrict__ vpk) {
  __shared__ unsigned short Alds[128 * 64];  // rows of 64 shorts (128B), swizzled
  __shared__ unsigned short Blds[128 * 64];

  const int m0 = blockIdx.x * 128;
  const int n0 = blockIdx.y * 128;  // 0 / 128 / 256 -> q / k / v
  const int tid = threadIdx.x;
  const int wave = tid >> 6, lane = tid & 63;
  const int g = lane >> 4, lr = lane & 15;
  const int wm = wave >> 2, wn = wave & 3;  // wave tile: 64 rows x 32 cols

  const int srow = lane >> 3;             // row within 8-row chunk
  const int sslot = lane & 7;             // 16B slot
  const int sksw = ((sslot ^ srow) * 8);  // pre-swizzled k-offset (shorts)

  f32x4 acc[4][2] = {};

  for (int kb = 0; kb < DM; kb += 64) {
    __syncthreads();  // readers done with LDS
#pragma unroll
    for (int i = 0; i < 2; ++i) {
      int ch = wave * 2 + i;  // chunk id 0..15, covers rows 8ch..8ch+7
      GLDS16(&xbf[(size_t)(m0 + ch * 8 + srow) * DM + kb + sksw],
             (char*)Alds + ch * 1024);
      GLDS16(&WqT[(size_t)(n0 + ch * 8 + srow) * DM + kb + sksw],
             (char*)Blds + ch * 1024);
    }
    asm volatile("s_waitcnt vmcnt(0)" ::: "memory");
    __syncthreads();

#pragma unroll
    for (int c2 = 0; c2 < 2; ++c2) {
      bf16x8_t ar[4], br[2];
#pragma unroll
      for (int mi = 0; mi < 4; ++mi) {
        int row = wm * 64 + mi * 16 + lr;
        ar[mi] = *(const bf16x8_t*)&Alds[row * 64 + (((c2 * 4 + g) ^ (row & 7)) * 8)];
      }
#pragma unroll
      for (int ni = 0; ni < 2; ++ni) {
        int row = wn * 32 + ni * 16 + lr;
        br[ni] = *(const bf16x8_t*)&Blds[row * 64 + (((c2 * 4 + g) ^ (row & 7)) * 8)];
      }
#pragma unroll
      for (int mi = 0; mi < 4; ++mi)
#pragma unroll
        for (int ni = 0; ni < 2; ++ni)
          acc[mi][ni] = __builtin_amdgcn_mfma_f32_16x16x32_bf16(ar[mi], br[ni],
                                                                acc[mi][ni], 0, 0, 0);
    }
  }

  if (n0 == 0) {  // Q: row-major, pre-scaled
#pragma unroll
    for (int ni = 0; ni < 2; ++ni) {
      int col = wn * 32 + ni * 16 + lr;
      float bv = bias[col];
#pragma unroll
      for (int mi = 0; mi < 4; ++mi) {
        int tokb = m0 + wm * 64 + mi * 16 + 4 * g;
#pragma unroll
        for (int r = 0; r < 4; ++r)
          qbf[(size_t)(tokb + r) * DA + col] = f2bf((acc[mi][ni][r] + bv) * QSC);
      }
    }
  } else if (n0 == 128) {  // K packed
#pragma unroll
    for (int ni = 0; ni < 2; ++ni) {
      int kd = wn * 32 + ni * 16 + lr;
      float bv = bias[128 + kd];
      int unit = (kd >> 5) * 4 + ((kd >> 3) & 3);  // c*4+gk (ct added per token)
      int elem = kd & 7;
#pragma unroll
      for (int mi = 0; mi < 4; ++mi) {
        int tokb = m0 + wm * 64 + mi * 16 + 4 * g;
#pragma unroll
        for (int r = 0; r < 4; ++r) {
          int token = tokb + r;
          int tile32 = token >> 5;
          int u = (((token >> 4) & 1) * 16) + unit;
          kpk[(size_t)tile32 * 4096 + u * 128 + (token & 15) * 8 + elem] =
              f2bf(acc[mi][ni][r] + bv);
        }
      }
    }
  } else {  // V packed, sigma-permuted
#pragma unroll
    for (int mi = 0; mi < 4; ++mi) {
      int keyb = m0 + wm * 64 + mi * 16 + 4 * g;  // 4-aligned
      int tile32 = keyb >> 5;
      int kl0 = keyb & 31;
      int gp = (kl0 >> 2) & 3;
      int jhi = kl0 >> 4;
#pragma unroll
      for (int ni = 0; ni < 2; ++ni) {
        int d = wn * 32 + ni * 16 + lr;
        float bv = bias[256 + d];
        union { bf16x4_t v; unsigned short u[4]; } pk;
#pragma unroll
        for (int r = 0; r < 4; ++r) pk.u[r] = f2bf(acc[mi][ni][r] + bv);
        int unit = (d >> 4) * 4 + gp;
        *(bf16x4_t*)&vpk[(size_t)tile32 * 4096 + unit * 128 + (d & 15) * 8 + jhi * 4] =
            pk.v;
      }
    }
  }
}

// ---------------------------------------------------------------------------
// Kernel 2: split-KV causal flash attention, swapped-QK (S^T), KVBLK=32,
// chunk = 640 keys, dbuf 32KB LDS (5 blocks/CU), counted vmcnt(4).
// Lane (g,lr) of wave w owns q-row qt*64 + w*16 + lr (as S^T column lr).
// sacc[ct][r] = S^T[key 16ct+4g+r][q lr], log2 domain.
// ---------------------------------------------------------------------------
__global__ __launch_bounds__(256, 5) void attn_kernel(
    const unsigned short* __restrict__ qbf, const unsigned short* __restrict__ kpk,
    const unsigned short* __restrict__ vpk, const float* __restrict__ key_mask,
    unsigned short* __restrict__ part_o, float* __restrict__ part_ml,
    unsigned short* __restrict__ ctx) {
  __shared__ unsigned short KV[2][8192];  // per buf: K shorts 0..4095, V 4096..8191

  const int flat = blockIdx.x;
  const int b = flat & 3;
  const int idxr = flat >> 2;  // 0..237, LPT: idxr 0 -> qt=63
  int rem = idxr;
  int qt = 63;
  for (;;) {
    int nc = (qt + 10) / 10;
    if (rem < nc) break;
    rem -= nc;
    --qt;
  }
  const int ci = rem;
  const bool direct = (qt < 10);  // single-chunk q-tile
  const int key0 = ci * 640;
  const int nkeys = min(640, (qt + 1) * 64 - key0);
  const int nt = nkeys >> 5;  // 32-key tiles, >= 2 always

  const int tid = threadIdx.x;
  const int wave = tid >> 6, lane = tid & 63;
  const int g = lane >> 4, lr = lane & 15;
  const int qloc = wave * 16 + lr;

  bf16x8_t qf[4];
  {
    const unsigned short* qb =
        qbf + ((size_t)(b * SEQ + qt * 64 + qloc)) * DA + g * 8;
#pragma unroll
    for (int c = 0; c < 4; ++c) qf[c] = *(const bf16x8_t*)(qb + c * 32);
  }

  f32x4 oacc[8] = {};
  float m_r = -INFINITY, l_r = 0.f;

  const int t32b = b * 128 + ci * 20;  // first 32-key tile (global index)
  const unsigned short* ksrc = kpk + (size_t)t32b * 4096 + wave * 1024 + lane * 8;
  const unsigned short* vsrc = vpk + (size_t)t32b * 4096 + wave * 1024 + lane * 8;

#define STAGE(buf, tt)                                                       \
  do {                                                                       \
    char* kd_ = (char*)&KV[buf][0] + wave * 2048;                            \
    char* vd_ = (char*)&KV[buf][4096] + wave * 2048;                         \
    _Pragma("unroll")                                                        \
    for (int i_ = 0; i_ < 2; ++i_) {                                         \
      GLDS16(ksrc + (size_t)(tt) * 4096 + i_ * 512, kd_ + i_ * 1024);        \
      GLDS16(vsrc + (size_t)(tt) * 4096 + i_ * 512, vd_ + i_ * 1024);        \
    }                                                                        \
  } while (0)

  STAGE(0, 0);  // prologue

  for (int tt = 0; tt < nt; ++tt) {
    const int cur = tt & 1;
    if (tt + 1 < nt) {
      STAGE(cur ^ 1, tt + 1);
      asm volatile("s_waitcnt vmcnt(4)" ::: "memory");  // current tile's 4 done
    } else {
      asm volatile("s_waitcnt vmcnt(0)" ::: "memory");
    }
    __builtin_amdgcn_s_barrier();
    __builtin_amdgcn_sched_barrier(0);

    // ---- QK^T (swapped) ----
    f32x4 sacc[2] = {};
    __builtin_amdgcn_s_setprio(1);
#pragma unroll
    for (int ct = 0; ct < 2; ++ct)
#pragma unroll
      for (int c = 0; c < 4; ++c) {
        bf16x8_t kf = *(const bf16x8_t*)&KV[cur][((ct * 16 + c * 4 + g) * 16 + lr) * 8];
        sacc[ct] = __builtin_amdgcn_mfma_f32_16x16x32_bf16(kf, qf[c], sacc[ct], 0, 0, 0);
      }
    __builtin_amdgcn_s_setprio(0);

    // ---- causal mask (near-diagonal tiles only) ----
    const int koff = key0 + tt * 32 - qt * 64;
    if (koff + 31 > wave * 16) {
      int thr = qloc - koff;
#pragma unroll
      for (int ct = 0; ct < 2; ++ct)
#pragma unroll
        for (int r = 0; r < 4; ++r)
          if (16 * ct + 4 * g + r > thr) sacc[ct][r] = -INFINITY;
    }

    // ---- online softmax (log2 domain) ----
    float tmax = fmaxf(fmaxf(fmaxf(sacc[0][0], sacc[0][1]), fmaxf(sacc[0][2], sacc[0][3])),
                       fmaxf(fmaxf(sacc[1][0], sacc[1][1]), fmaxf(sacc[1][2], sacc[1][3])));
    tmax = fmaxf(tmax, __shfl_xor(tmax, 16, 64));
    tmax = fmaxf(tmax, __shfl_xor(tmax, 32, 64));

    if (!__all(tmax <= m_r + 10.0f)) {
      float mn = fmaxf(m_r, tmax);
      float al = fexp2(m_r - mn);
      m_r = mn;
      l_r *= al;
#pragma unroll
      for (int t = 0; t < 8; ++t)
#pragma unroll
        for (int r = 0; r < 4; ++r) oacc[t][r] *= al;
    }

    float rs = 0.f;
#pragma unroll
    for (int ct = 0; ct < 2; ++ct)
#pragma unroll
      for (int r = 0; r < 4; ++r) {
        float p = fexp2(sacc[ct][r] - m_r);
        sacc[ct][r] = p;
        rs += p;
      }
    rs += __shfl_xor(rs, 16, 64);
    rs += __shfl_xor(rs, 32, 64);
    l_r += rs;

    // ---- P B-frag from registers (sigma-permuted keys) ----
    bf16x8_t pb;
    {
      union { unsigned u[4]; bf16x8_t v; } pk;
      pk.u[0] = pkbf(sacc[0][0], sacc[0][1]);
      pk.u[1] = pkbf(sacc[0][2], sacc[0][3]);
      pk.u[2] = pkbf(sacc[1][0], sacc[1][1]);
      pk.u[3] = pkbf(sacc[1][2], sacc[1][3]);
      pb = pk.v;
    }

    // ---- PV ----
    __builtin_amdgcn_s_setprio(1);
#pragma unroll
    for (int t = 0; t < 8; ++t) {
      bf16x8_t vf = *(const bf16x8_t*)&KV[cur][4096 + ((t * 4 + g) * 16 + lr) * 8];
      oacc[t] = __builtin_amdgcn_mfma_f32_16x16x32_bf16(vf, pb, oacc[t], 0, 0, 0);
    }
    __builtin_amdgcn_s_setprio(0);

    __builtin_amdgcn_s_barrier();  // protect buf before next STAGE overwrite
  }
#undef STAGE

  // ---- epilogue: lane owns q-row qloc; d = 16t + 4g + r ----
  const int row = qloc;
  if (direct) {
    float km = key_mask[b * SEQ + qt * 64 + row];
    float inv = km / l_r;
    unsigned short* co = ctx + ((size_t)(b * SEQ + qt * 64 + row)) * DA;
#pragma unroll
    for (int t = 0; t < 8; ++t) {
      union { bf16x4_t v; unsigned short u[4]; } pk;
#pragma unroll
      for (int r = 0; r < 4; ++r) pk.u[r] = f2bf(oacc[t][r] * inv);
      *(bf16x4_t*)&co[t * 16 + 4 * g] = pk.v;
    }
  } else {
    const int slot = b * IPB + idxr;
    unsigned short* po = part_o + (size_t)slot * 8192 + row * 128;
#pragma unroll
    for (int t = 0; t < 8; ++t) {
      union { bf16x4_t v; unsigned short u[4]; } pk;
#pragma unroll
      for (int r = 0; r < 4; ++r) pk.u[r] = f2bf(oacc[t][r]);
      *(bf16x4_t*)&po[t * 16 + 4 * g] = pk.v;
    }
    if (g == 0) {
      float2 ml = make_float2(m_r, l_r);
      *(float2*)&part_ml[((size_t)slot * 64 + row) * 2] = ml;
    }
  }
}

// ---------------------------------------------------------------------------
// Kernel 2b: combine partials -> ctx for qt >= 10.  grid (54, 4).
// ---------------------------------------------------------------------------
__global__ __launch_bounds__(256) void combine_kernel(
    const unsigned short* __restrict__ part_o, const float* __restrict__ part_ml,
    const float* __restrict__ key_mask, unsigned short* __restrict__ ctx) {
  const int qt = 10 + blockIdx.x;
  const int b = blockIdx.y;
  const int nc = (qt + 10) / 10;
  int idx0 = 0;
  for (int q = 63; q > qt; --q) idx0 += (q + 10) / 10;
  const int row = threadIdx.x >> 2, cg = threadIdx.x & 3;

  float m = -INFINITY;
  for (int ci = 0; ci < nc; ++ci) {
    int slot = b * IPB + idx0 + ci;
    m = fmaxf(m, part_ml[((size_t)slot * 64 + row) * 2 + 0]);
  }
  float l = 0.f;
  float acc[32];
#pragma unroll
  for (int k = 0; k < 32; ++k) acc[k] = 0.f;
  for (int ci = 0; ci < nc; ++ci) {
    int slot = b * IPB + idx0 + ci;
    float mi = part_ml[((size_t)slot * 64 + row) * 2 + 0];
    float li = part_ml[((size_t)slot * 64 + row) * 2 + 1];
    float w = fexp2(mi - m);
    l += w * li;
    const unsigned short* po = part_o + (size_t)slot * 8192 + row * 128 + cg * 32;
#pragma unroll
    for (int k8 = 0; k8 < 4; ++k8) {
      bf16x8_t v = *(const bf16x8_t*)(po + k8 * 8);
#pragma unroll
      for (int jj = 0; jj < 8; ++jj)
        acc[k8 * 8 + jj] += w * bf2f((unsigned short)v[jj]);
    }
  }
  int rowg = (b * 64 + qt) * 64 + row;
  float sc = key_mask[rowg] / l;
  unsigned short* co = ctx + (size_t)rowg * 128 + cg * 32;
#pragma unroll
  for (int k8 = 0; k8 < 4; ++k8) {
    union { bf16x8_t v; unsigned short u[8]; } pk;
#pragma unroll
    for (int jj = 0; jj < 8; ++jj) pk.u[jj] = f2bf(acc[k8 * 8 + jj] * sc);
    *(bf16x8_t*)(co + k8 * 8) = pk.v;
  }
}

// ---------------------------------------------------------------------------
// Kernel 3: output projection.  [16384,128] @ [128,512] + bias -> fp32 out
// ---------------------------------------------------------------------------
__global__ __launch_bounds__(256) void outproj_kernel(
    const unsigned short* __restrict__ ctx, const unsigned short* __restrict__ WoT,
    const float* __restrict__ bias, float* __restrict__ out) {
  __shared__ unsigned short Alds[64 * 32];
  __shared__ unsigned short Blds[64 * 32];

  const int m0 = blockIdx.x * 64;
  const int n0 = blockIdx.y * 64;
  const int tid = threadIdx.x;
  const int wave = tid >> 6, lane = tid & 63;
  const int g = lane >> 4, lr = lane & 15;
  const int sar = tid >> 2, sak = tid & 3;
  const int sbc = tid & 63, sbk = tid >> 6;

  f32x4 acc[4] = {};

  for (int kb = 0; kb < DA; kb += 32) {
    __syncthreads();
    {
      bf16x8_t v = *(const bf16x8_t*)&ctx[(size_t)(m0 + sar) * DA + kb + sak * 8];
      *(bf16x8_t*)&Alds[(((sar >> 4) * 4 + sak) * 16 + (sar & 15)) * 8] = v;
    }
    {
      bf16x8_t v = *(const bf16x8_t*)&WoT[(size_t)(n0 + sbc) * DA + kb + sbk * 8];
      *(bf16x8_t*)&Blds[(((sbc >> 4) * 4 + sbk) * 16 + (sbc & 15)) * 8] = v;
    }
    __syncthreads();
    bf16x8_t af = *(const bf16x8_t*)&Alds[((wave * 4 + g) * 16 + lr) * 8];
#pragma unroll
    for (int c = 0; c < 4; ++c) {
      bf16x8_t bfr = *(const bf16x8_t*)&Blds[((c * 4 + g) * 16 + lr) * 8];
      acc[c] = __builtin_amdgcn_mfma_f32_16x16x32_bf16(af, bfr, acc[c], 0, 0, 0);
    }
  }

  const int rowb = m0 + wave * 16 + g * 4;
#pragma unroll
  for (int c = 0; c < 4; ++c) {
    int col = n0 + c * 16 + lr;
    float bv = bias[col];
#pragma unroll
    for (int r = 0; r < 4; ++r)
      out[(size_t)(rowb + r) * DM + col] = acc[c][r] + bv;
  }
}

// ---------------------------------------------------------------------------
extern "C" void kernel_launch(void* const* d_in, const int* in_sizes, int n_in,
                              void* d_out, int out_size, void* d_ws, size_t ws_size,
                              hipStream_t stream) {
  const float* x = (const float*)d_in[0];
  const float* key_mask = (const float*)d_in[1];
  const float* W_qkv = (const float*)d_in[2];
  const float* b_qkv = (const float*)d_in[3];
  const float* W_out = (const float*)d_in[4];
  const float* b_out = (const float*)d_in[5];
  float* out = (float*)d_out;

  unsigned short* ws = (unsigned short*)d_ws;
  unsigned short* qbf = ws;                        // [BN][128] bf16 (pre-scaled)
  unsigned short* kpk = qbf + (size_t)BN * DA;     // packed K 32-tiles
  unsigned short* vpk = kpk + (size_t)BN * DA;     // packed V 32-tiles (sigma)
  unsigned short* ctx = vpk + (size_t)BN * DA;     // [BN][128] bf16
  unsigned short* xbf = ctx + (size_t)BN * DA;     // [BN][512] bf16 (dead after qkv)
  unsigned short* WqT = xbf + (size_t)BN * DM;     // [384][512]
  unsigned short* WoT = WqT + (size_t)384 * 512;   // [512][128]

  // reuse xbf region for attention partials (15.9 MB < 16.8 MB)
  unsigned short* part_o = xbf;                    // [952][64][128] bf16
  float* part_ml = (float*)(xbf + (size_t)N_ITEMS * 8192);  // [952][64][2] f32

  prep_kernel<<<dim3((BN * DM / 8 + 255) / 256), 256, 0, stream>>>(
      x, W_qkv, W_out, xbf, WqT, WoT);
  qkv_kernel<<<dim3(BN / 128, 3), 512, 0, stream>>>(xbf, WqT, b_qkv, qbf, kpk, vpk);
  attn_kernel<<<dim3(N_ITEMS), 256, 0, stream>>>(qbf, kpk, vpk, key_mask,
                                                 part_o, part_ml, ctx);
  combine_kernel<<<dim3(54, 4), 256, 0, stream>>>(part_o, part_ml, key_mask, ctx);
  outproj_kernel<<<dim3(BN / 64, 8), 256, 0, stream>>>(ctx, WoT, b_out, out);
}